// Round 1
// baseline (596.260 us; speedup 1.0000x reference)
//
#include <hip/hip_runtime.h>
#include <math.h>

#define D_IN  256
#define D_H   64
#define D_OUT 16

// ---------------------------------------------------------------------------
// GEMM1: h1[n,64] = x[n,256] @ W1[256,64].  W1 (64KB) staged in LDS.
// 1024 threads/block, 64 rows/block, each thread = 1 row x 4 cols (float4 acc).
// ---------------------------------------------------------------------------
__global__ __launch_bounds__(1024) void k_gemm1(const float* __restrict__ x,
                                                const float* __restrict__ W1,
                                                float* __restrict__ h1, int n) {
    __shared__ float w1s[D_IN * D_H];  // 64 KB
    int t = threadIdx.x;
    const float4* w1g4 = (const float4*)W1;
    float4* w1s4 = (float4*)w1s;
#pragma unroll
    for (int j = 0; j < 4; ++j) w1s4[t + j * 1024] = w1g4[t + j * 1024];
    __syncthreads();

    int cgrp = t & 15;                      // cols cgrp*4 .. cgrp*4+3
    int row  = blockIdx.x * 64 + (t >> 4);
    if (row >= n) return;

    const float4* xr = (const float4*)(x + (size_t)row * D_IN);
    float4 acc = {0.f, 0.f, 0.f, 0.f};
#pragma unroll 4
    for (int k4 = 0; k4 < D_IN / 4; ++k4) {
        float4 xv = xr[k4];
#pragma unroll
        for (int kk = 0; kk < 4; ++kk) {
            float4 wv = w1s4[(k4 * 4 + kk) * 16 + cgrp];
            float xs = (&xv.x)[kk];
            acc.x += xs * wv.x; acc.y += xs * wv.y;
            acc.z += xs * wv.z; acc.w += xs * wv.w;
        }
    }
    ((float4*)(h1 + (size_t)row * D_H))[cgrp] = acc;
}

// ---------------------------------------------------------------------------
// CSR build: histogram -> 2-level exclusive scan -> scatter
// ---------------------------------------------------------------------------
__global__ void k_hist(const int* __restrict__ ei, int* __restrict__ counts, int e_cnt) {
    int e = blockIdx.x * blockDim.x + threadIdx.x;
    if (e < e_cnt) atomicAdd(&counts[ei[e]], 1);  // ei[0..E) = dst row
}

// 256 threads, 4 items/thread => 1024 elements/block
__global__ __launch_bounds__(256) void k_scanA(const int* __restrict__ counts,
                                               int* __restrict__ exOut,
                                               int* __restrict__ blockSum, int n) {
    __shared__ int lds[256];
    int t = threadIdx.x;
    int base = blockIdx.x * 1024 + t * 4;
    int c0 = (base + 0 < n) ? counts[base + 0] : 0;
    int c1 = (base + 1 < n) ? counts[base + 1] : 0;
    int c2 = (base + 2 < n) ? counts[base + 2] : 0;
    int c3 = (base + 3 < n) ? counts[base + 3] : 0;
    int tsum = c0 + c1 + c2 + c3;
    lds[t] = tsum;
    __syncthreads();
    for (int off = 1; off < 256; off <<= 1) {
        int v = (t >= off) ? lds[t - off] : 0;
        __syncthreads();
        lds[t] += v;
        __syncthreads();
    }
    int exBase = lds[t] - tsum;  // exclusive prefix of thread sums
    if (t == 0) blockSum[blockIdx.x] = lds[255];
    if (base + 0 < n) exOut[base + 0] = exBase;
    if (base + 1 < n) exOut[base + 1] = exBase + c0;
    if (base + 2 < n) exOut[base + 2] = exBase + c0 + c1;
    if (base + 3 < n) exOut[base + 3] = exBase + c0 + c1 + c2;
}

__global__ void k_scanB(const int* __restrict__ blockSum, int* __restrict__ blockOff,
                        int* __restrict__ offsets, int nb, int n) {
    if (blockIdx.x == 0 && threadIdx.x == 0) {
        int run = 0;
        for (int b = 0; b < nb; ++b) { blockOff[b] = run; run += blockSum[b]; }
        offsets[n] = run;  // == e_cnt
    }
}

__global__ void k_scanC(const int* __restrict__ exOut, const int* __restrict__ blockOff,
                        int* __restrict__ offsets, int* __restrict__ cursor, int n) {
    int i = blockIdx.x * blockDim.x + threadIdx.x;
    if (i < n) {
        int v = exOut[i] + blockOff[i >> 10];
        offsets[i] = v;
        cursor[i] = v;
    }
}

__global__ void k_scatter(const int* __restrict__ ei, const float* __restrict__ vals,
                          int* __restrict__ cursor, int* __restrict__ srcS,
                          float* __restrict__ valS, int e_cnt) {
    int e = blockIdx.x * blockDim.x + threadIdx.x;
    if (e < e_cnt) {
        int d = ei[e];
        int s = ei[e_cnt + e];  // ei[E..2E) = src row
        float v = vals[e];
        int p = atomicAdd(&cursor[d], 1);
        srcS[p] = s;
        valS[p] = v;
    }
}

// ---------------------------------------------------------------------------
// SpMM1 + ReLU: a1[dst,0:64] = relu( sum_e val_e * h1[src_e, 0:64] )
// one 64-lane wave per dst row; lane = feature. No atomics.
// ---------------------------------------------------------------------------
__global__ __launch_bounds__(256) void k_spmm1(const int* __restrict__ offsets,
                                               const int* __restrict__ srcS,
                                               const float* __restrict__ valS,
                                               const float* __restrict__ h1,
                                               float* __restrict__ a1, int n) {
    int lane = threadIdx.x & 63;
    int dst = blockIdx.x * 4 + (threadIdx.x >> 6);
    if (dst >= n) return;
    int e0 = offsets[dst], e1 = offsets[dst + 1];
    float acc = 0.f;
    for (int e = e0; e < e1; ++e) {
        int s = srcS[e];
        float v = valS[e];
        acc += v * h1[(size_t)s * D_H + lane];
    }
    a1[(size_t)dst * D_H + lane] = fmaxf(acc, 0.f);
}

// ---------------------------------------------------------------------------
// GEMM2: h2[n,16] = a1[n,64] @ W2[64,16].  W2 (4KB) in LDS.
// 256 threads/block, 64 nodes/block, thread = 1 node x 4 cols.
// ---------------------------------------------------------------------------
__global__ __launch_bounds__(256) void k_gemm2(const float* __restrict__ a1,
                                               const float* __restrict__ W2,
                                               float* __restrict__ h2, int n) {
    __shared__ float w2s[D_H * D_OUT];  // 1024 floats
    int t = threadIdx.x;
#pragma unroll
    for (int j = 0; j < 4; ++j) w2s[t + j * 256] = W2[t + j * 256];
    __syncthreads();

    int cgrp = t & 3;
    int node = blockIdx.x * 64 + (t >> 2);
    if (node >= n) return;

    const float4* ar = (const float4*)(a1 + (size_t)node * D_H);
    const float4* w2s4 = (const float4*)w2s;
    float4 acc = {0.f, 0.f, 0.f, 0.f};
#pragma unroll
    for (int k4 = 0; k4 < D_H / 4; ++k4) {
        float4 av = ar[k4];
#pragma unroll
        for (int kk = 0; kk < 4; ++kk) {
            float4 wv = w2s4[(k4 * 4 + kk) * 4 + cgrp];
            float s = (&av.x)[kk];
            acc.x += s * wv.x; acc.y += s * wv.y;
            acc.z += s * wv.z; acc.w += s * wv.w;
        }
    }
    ((float4*)(h2 + (size_t)node * D_OUT))[cgrp] = acc;
}

// ---------------------------------------------------------------------------
// SpMM2 + log_softmax: out[dst,0:16] = logsoftmax( sum_e val_e * h2[src_e,0:16] )
// 16 lanes per dst; softmax via __shfl_xor within the 16-lane group.
// ---------------------------------------------------------------------------
__global__ __launch_bounds__(256) void k_spmm2(const int* __restrict__ offsets,
                                               const int* __restrict__ srcS,
                                               const float* __restrict__ valS,
                                               const float* __restrict__ h2,
                                               float* __restrict__ out, int n) {
    int f = threadIdx.x & 15;
    int dst = blockIdx.x * 16 + (threadIdx.x >> 4);
    if (dst >= n) return;
    int e0 = offsets[dst], e1 = offsets[dst + 1];
    float acc = 0.f;
    for (int e = e0; e < e1; ++e) {
        int s = srcS[e];
        float v = valS[e];
        acc += v * h2[(size_t)s * D_OUT + f];
    }
    float m = acc;
#pragma unroll
    for (int d = 1; d < 16; d <<= 1) m = fmaxf(m, __shfl_xor(m, d, 16));
    float ex = expf(acc - m);
    float sum = ex;
#pragma unroll
    for (int d = 1; d < 16; d <<= 1) sum += __shfl_xor(sum, d, 16);
    out[(size_t)dst * D_OUT + f] = acc - m - logf(sum);
}

// ---------------------------------------------------------------------------
extern "C" void kernel_launch(void* const* d_in, const int* in_sizes, int n_in,
                              void* d_out, int out_size, void* d_ws, size_t ws_size,
                              hipStream_t stream) {
    const float* x  = (const float*)d_in[0];
    const float* W1 = (const float*)d_in[1];
    const float* W2 = (const float*)d_in[2];
    const float* ev = (const float*)d_in[3];
    const int*   ei = (const int*)d_in[4];
    float* out = (float*)d_out;

    int n     = in_sizes[0] / D_IN;  // 100000
    int e_cnt = in_sizes[3];         // 1600000

    // workspace layout (all 4-byte types, base is 256B-aligned)
    float* h1      = (float*)d_ws;               // n*64
    float* a1      = h1 + (size_t)n * D_H;       // n*64
    float* h2      = a1 + (size_t)n * D_H;       // n*16
    int*   counts  = (int*)(h2 + (size_t)n * D_OUT);  // n
    int*   exOut   = counts + n;                 // n
    int*   blockSum = exOut + n;                 // <=128
    int*   blockOff = blockSum + 128;            // <=128
    int*   offsets = blockOff + 128;             // n+1
    int*   cursor  = offsets + n + 31;           // n
    int*   srcS    = cursor + n;                 // e_cnt
    float* valS    = (float*)(srcS + e_cnt);     // e_cnt

    hipMemsetAsync(counts, 0, (size_t)n * sizeof(int), stream);

    int nb_scan = (n + 1023) / 1024;

    k_gemm1  <<<(n + 63) / 64, 1024, 0, stream>>>(x, W1, h1, n);
    k_hist   <<<(e_cnt + 255) / 256, 256, 0, stream>>>(ei, counts, e_cnt);
    k_scanA  <<<nb_scan, 256, 0, stream>>>(counts, exOut, blockSum, n);
    k_scanB  <<<1, 1, 0, stream>>>(blockSum, blockOff, offsets, nb_scan, n);
    k_scanC  <<<(n + 255) / 256, 256, 0, stream>>>(exOut, blockOff, offsets, cursor, n);
    k_scatter<<<(e_cnt + 255) / 256, 256, 0, stream>>>(ei, ev, cursor, srcS, valS, e_cnt);
    k_spmm1  <<<(n + 3) / 4, 256, 0, stream>>>(offsets, srcS, valS, h1, a1, n);
    k_gemm2  <<<(n + 63) / 64, 256, 0, stream>>>(a1, W2, h2, n);
    k_spmm2  <<<(n + 15) / 16, 256, 0, stream>>>(offsets, srcS, valS, h2, out, n);
}

// Round 2
// 515.060 us; speedup vs baseline: 1.1577x; 1.1577x over previous
//
#include <hip/hip_runtime.h>
#include <hip/hip_fp16.h>
#include <math.h>

#define D_IN  256
#define D_H   64
#define D_OUT 16

// ---------------------------------------------------------------------------
// GEMM1: h1[n,64] = x[n,256] @ W1[256,64], output stored as fp16.
// 1024 threads/block, 64 rows/block, each thread = 1 row x 4 cols.
// ---------------------------------------------------------------------------
__global__ __launch_bounds__(1024) void k_gemm1(const float* __restrict__ x,
                                                const float* __restrict__ W1,
                                                __half* __restrict__ h1h, int n) {
    __shared__ float w1s[D_IN * D_H];  // 64 KB
    int t = threadIdx.x;
    const float4* w1g4 = (const float4*)W1;
    float4* w1s4 = (float4*)w1s;
#pragma unroll
    for (int j = 0; j < 4; ++j) w1s4[t + j * 1024] = w1g4[t + j * 1024];
    __syncthreads();

    int cgrp = t & 15;                      // cols cgrp*4 .. cgrp*4+3
    int row  = blockIdx.x * 64 + (t >> 4);
    if (row >= n) return;

    const float4* xr = (const float4*)(x + (size_t)row * D_IN);
    float4 acc = {0.f, 0.f, 0.f, 0.f};
#pragma unroll 4
    for (int k4 = 0; k4 < D_IN / 4; ++k4) {
        float4 xv = xr[k4];
#pragma unroll
        for (int kk = 0; kk < 4; ++kk) {
            float4 wv = w1s4[(k4 * 4 + kk) * 16 + cgrp];
            float xs = (&xv.x)[kk];
            acc.x += xs * wv.x; acc.y += xs * wv.y;
            acc.z += xs * wv.z; acc.w += xs * wv.w;
        }
    }
    __half2* o2 = (__half2*)(h1h + (size_t)row * D_H);
    o2[cgrp * 2 + 0] = __floats2half2_rn(acc.x, acc.y);
    o2[cgrp * 2 + 1] = __floats2half2_rn(acc.z, acc.w);
}

// ---------------------------------------------------------------------------
// CSR build: histogram -> 2-level exclusive scan -> scatter (packed int2)
// ---------------------------------------------------------------------------
__global__ void k_hist(const int* __restrict__ ei, int* __restrict__ counts, int e_cnt) {
    int e = blockIdx.x * blockDim.x + threadIdx.x;
    if (e < e_cnt) atomicAdd(&counts[ei[e]], 1);  // ei[0..E) = dst row
}

// 256 threads, 4 items/thread => 1024 elements/block
__global__ __launch_bounds__(256) void k_scanA(const int* __restrict__ counts,
                                               int* __restrict__ exOut,
                                               int* __restrict__ blockSum, int n) {
    __shared__ int lds[256];
    int t = threadIdx.x;
    int base = blockIdx.x * 1024 + t * 4;
    int c0 = (base + 0 < n) ? counts[base + 0] : 0;
    int c1 = (base + 1 < n) ? counts[base + 1] : 0;
    int c2 = (base + 2 < n) ? counts[base + 2] : 0;
    int c3 = (base + 3 < n) ? counts[base + 3] : 0;
    int tsum = c0 + c1 + c2 + c3;
    lds[t] = tsum;
    __syncthreads();
    for (int off = 1; off < 256; off <<= 1) {
        int v = (t >= off) ? lds[t - off] : 0;
        __syncthreads();
        lds[t] += v;
        __syncthreads();
    }
    int exBase = lds[t] - tsum;  // exclusive prefix of thread sums
    if (t == 0) blockSum[blockIdx.x] = lds[255];
    if (base + 0 < n) exOut[base + 0] = exBase;
    if (base + 1 < n) exOut[base + 1] = exBase + c0;
    if (base + 2 < n) exOut[base + 2] = exBase + c0 + c1;
    if (base + 3 < n) exOut[base + 3] = exBase + c0 + c1 + c2;
}

// parallel scan over block sums (nb <= 128)
__global__ __launch_bounds__(128) void k_scanB(const int* __restrict__ blockSum,
                                               int* __restrict__ blockOff,
                                               int* __restrict__ offsets, int nb, int n) {
    __shared__ int lds[128];
    int t = threadIdx.x;
    int v = (t < nb) ? blockSum[t] : 0;
    lds[t] = v;
    __syncthreads();
    for (int off = 1; off < 128; off <<= 1) {
        int u = (t >= off) ? lds[t - off] : 0;
        __syncthreads();
        lds[t] += u;
        __syncthreads();
    }
    if (t < nb) blockOff[t] = lds[t] - v;
    if (t == 127) offsets[n] = lds[127];
}

__global__ void k_scanC(const int* __restrict__ exOut, const int* __restrict__ blockOff,
                        int* __restrict__ offsets, int* __restrict__ cursor, int n) {
    int i = blockIdx.x * blockDim.x + threadIdx.x;
    if (i < n) {
        int v = exOut[i] + blockOff[i >> 10];
        offsets[i] = v;
        cursor[i] = v;
    }
}

__global__ void k_scatter(const int* __restrict__ ei, const float* __restrict__ vals,
                          int* __restrict__ cursor, int2* __restrict__ srcval, int e_cnt) {
    int e = blockIdx.x * blockDim.x + threadIdx.x;
    if (e < e_cnt) {
        int d = ei[e];
        int s = ei[e_cnt + e];  // ei[E..2E) = src row
        float v = vals[e];
        int p = atomicAdd(&cursor[d], 1);
        srcval[p] = make_int2(s, __float_as_int(v));  // one 8B store
    }
}

// ---------------------------------------------------------------------------
// Fused SpMM1 + ReLU + GEMM2:
//   a1[dst,:] = relu( sum_e val_e * h1[src_e,:] )   (register-resident)
//   h2[dst,0:16] = a1[dst,:] @ W2[64,16]            (LDS round-trip + shfl)
// one 64-lane wave per dst row; lane = feature. Edge loop unrolled x4 for MLP.
// ---------------------------------------------------------------------------
__global__ __launch_bounds__(256) void k_spmm1g2(const int* __restrict__ offsets,
                                                 const int2* __restrict__ sv,
                                                 const __half* __restrict__ h1h,
                                                 const float* __restrict__ W2,
                                                 __half* __restrict__ h2h, int n) {
    __shared__ float W2s[D_H * 17];    // padded stride 17 (bank spread)
    __shared__ float rbuf[4][D_H];
    int t = threadIdx.x;
    for (int i = t; i < D_H * D_OUT; i += 256)
        W2s[(i >> 4) * 17 + (i & 15)] = W2[i];

    int lane = t & 63, wid = t >> 6;
    int dst = blockIdx.x * 4 + wid;
    bool valid = dst < n;
    int e0 = 0, e1 = 0;
    if (valid) { e0 = offsets[dst]; e1 = offsets[dst + 1]; }

    float acc = 0.f;
    int e = e0;
    for (; e + 4 <= e1; e += 4) {
        int2 A = sv[e], B = sv[e + 1], C = sv[e + 2], D = sv[e + 3];
        float g0 = __half2float(h1h[(size_t)A.x * D_H + lane]);
        float g1 = __half2float(h1h[(size_t)B.x * D_H + lane]);
        float g2 = __half2float(h1h[(size_t)C.x * D_H + lane]);
        float g3 = __half2float(h1h[(size_t)D.x * D_H + lane]);
        acc = fmaf(__int_as_float(A.y), g0, acc);
        acc = fmaf(__int_as_float(B.y), g1, acc);
        acc = fmaf(__int_as_float(C.y), g2, acc);
        acc = fmaf(__int_as_float(D.y), g3, acc);
    }
    for (; e < e1; ++e) {
        int2 A = sv[e];
        acc = fmaf(__int_as_float(A.y), __half2float(h1h[(size_t)A.x * D_H + lane]), acc);
    }
    rbuf[wid][lane] = fmaxf(acc, 0.f);   // relu
    __syncthreads();                      // covers W2s staging + rbuf

    // h2[dst][j] = sum_k rbuf[k] * W2[k][j];  lane -> (j = lane&15, k-range g = lane>>4)
    int j = lane & 15, g = lane >> 4;
    float s = 0.f;
#pragma unroll
    for (int kk = 0; kk < 16; ++kk)
        s = fmaf(rbuf[wid][g * 16 + kk], W2s[(g * 16 + kk) * 17 + j], s);
    s += __shfl_xor(s, 16);
    s += __shfl_xor(s, 32);
    if (valid && lane < 16) h2h[(size_t)dst * D_OUT + j] = __float2half(s);
}

// ---------------------------------------------------------------------------
// SpMM2 + log_softmax: out[dst,0:16] = logsoftmax( sum_e val_e * h2[src_e,0:16] )
// 16 lanes per dst; edge loop unrolled x4.
// ---------------------------------------------------------------------------
__global__ __launch_bounds__(256) void k_spmm2(const int* __restrict__ offsets,
                                               const int2* __restrict__ sv,
                                               const __half* __restrict__ h2h,
                                               float* __restrict__ out, int n) {
    int t = threadIdx.x;
    int f = t & 15;
    int dst = blockIdx.x * 16 + (t >> 4);
    if (dst >= n) return;
    int e0 = offsets[dst], e1 = offsets[dst + 1];
    float acc = 0.f;
    int e = e0;
    for (; e + 4 <= e1; e += 4) {
        int2 A = sv[e], B = sv[e + 1], C = sv[e + 2], D = sv[e + 3];
        float g0 = __half2float(h2h[(size_t)A.x * D_OUT + f]);
        float g1 = __half2float(h2h[(size_t)B.x * D_OUT + f]);
        float g2 = __half2float(h2h[(size_t)C.x * D_OUT + f]);
        float g3 = __half2float(h2h[(size_t)D.x * D_OUT + f]);
        acc = fmaf(__int_as_float(A.y), g0, acc);
        acc = fmaf(__int_as_float(B.y), g1, acc);
        acc = fmaf(__int_as_float(C.y), g2, acc);
        acc = fmaf(__int_as_float(D.y), g3, acc);
    }
    for (; e < e1; ++e) {
        int2 A = sv[e];
        acc = fmaf(__int_as_float(A.y), __half2float(h2h[(size_t)A.x * D_OUT + f]), acc);
    }
    float m = acc;
#pragma unroll
    for (int d = 1; d < 16; d <<= 1) m = fmaxf(m, __shfl_xor(m, d, 16));
    float ex = expf(acc - m);
    float sum = ex;
#pragma unroll
    for (int d = 1; d < 16; d <<= 1) sum += __shfl_xor(sum, d, 16);
    out[(size_t)dst * D_OUT + f] = acc - m - logf(sum);
}

// ---------------------------------------------------------------------------
extern "C" void kernel_launch(void* const* d_in, const int* in_sizes, int n_in,
                              void* d_out, int out_size, void* d_ws, size_t ws_size,
                              hipStream_t stream) {
    const float* x  = (const float*)d_in[0];
    const float* W1 = (const float*)d_in[1];
    const float* W2 = (const float*)d_in[2];
    const float* ev = (const float*)d_in[3];
    const int*   ei = (const int*)d_in[4];
    float* out = (float*)d_out;

    int n     = in_sizes[0] / D_IN;  // 100000
    int e_cnt = in_sizes[3];         // 1600000

    // workspace layout (srcval first for 8B alignment)
    int2*   srcval = (int2*)d_ws;                       // e_cnt
    __half* h1h    = (__half*)(srcval + e_cnt);         // n*64
    __half* h2h    = h1h + (size_t)n * D_H;             // n*16
    int* counts    = (int*)(h2h + (size_t)n * D_OUT);   // n
    int* exOut     = counts + n;                        // n
    int* blockSum  = exOut + n;                         // <=128
    int* blockOff  = blockSum + 128;                    // <=128
    int* offsets   = blockOff + 128;                    // n+1
    int* cursor    = offsets + n + 1;                   // n

    hipMemsetAsync(counts, 0, (size_t)n * sizeof(int), stream);

    int nb_scan = (n + 1023) / 1024;

    k_gemm1  <<<(n + 63) / 64, 1024, 0, stream>>>(x, W1, h1h, n);
    k_hist   <<<(e_cnt + 255) / 256, 256, 0, stream>>>(ei, counts, e_cnt);
    k_scanA  <<<nb_scan, 256, 0, stream>>>(counts, exOut, blockSum, n);
    k_scanB  <<<1, 128, 0, stream>>>(blockSum, blockOff, offsets, nb_scan, n);
    k_scanC  <<<(n + 255) / 256, 256, 0, stream>>>(exOut, blockOff, offsets, cursor, n);
    k_scatter<<<(e_cnt + 255) / 256, 256, 0, stream>>>(ei, ev, cursor, srcval, e_cnt);
    k_spmm1g2<<<(n + 3) / 4, 256, 0, stream>>>(offsets, srcval, h1h, W2, h2h, n);
    k_spmm2  <<<(n + 15) / 16, 256, 0, stream>>>(offsets, srcval, h2h, out, n);
}

// Round 5
// 474.664 us; speedup vs baseline: 1.2562x; 1.0851x over previous
//
#include <hip/hip_runtime.h>
#include <hip/hip_fp16.h>
#include <math.h>

#define D_IN  256
#define D_H   64
#define D_OUT 16

// ---------------------------------------------------------------------------
// GEMM1: h1[n,64] = x[n,256] @ W1[256,64], output stored as fp16.
// ---------------------------------------------------------------------------
__global__ __launch_bounds__(1024) void k_gemm1(const float* __restrict__ x,
                                                const float* __restrict__ W1,
                                                __half* __restrict__ h1h, int n) {
    __shared__ float w1s[D_IN * D_H];  // 64 KB
    int t = threadIdx.x;
    const float4* w1g4 = (const float4*)W1;
    float4* w1s4 = (float4*)w1s;
#pragma unroll
    for (int j = 0; j < 4; ++j) w1s4[t + j * 1024] = w1g4[t + j * 1024];
    __syncthreads();

    int cgrp = t & 15;                      // cols cgrp*4 .. cgrp*4+3
    int row  = blockIdx.x * 64 + (t >> 4);
    if (row >= n) return;

    const float4* xr = (const float4*)(x + (size_t)row * D_IN);
    float4 acc = {0.f, 0.f, 0.f, 0.f};
#pragma unroll 4
    for (int k4 = 0; k4 < D_IN / 4; ++k4) {
        float4 xv = xr[k4];
#pragma unroll
        for (int kk = 0; kk < 4; ++kk) {
            float4 wv = w1s4[(k4 * 4 + kk) * 16 + cgrp];
            float xs = (&xv.x)[kk];
            acc.x += xs * wv.x; acc.y += xs * wv.y;
            acc.z += xs * wv.z; acc.w += xs * wv.w;
        }
    }
    __half2* o2 = (__half2*)(h1h + (size_t)row * D_H);
    o2[cgrp * 2 + 0] = __floats2half2_rn(acc.x, acc.y);
    o2[cgrp * 2 + 1] = __floats2half2_rn(acc.z, acc.w);
}

// ---------------------------------------------------------------------------
// CSR build: histogram -> 2-level exclusive scan -> XCD-phased scatter
// ---------------------------------------------------------------------------
__global__ void k_hist(const int* __restrict__ ei, int* __restrict__ counts, int e_cnt) {
    int e = blockIdx.x * blockDim.x + threadIdx.x;
    if (e < e_cnt) atomicAdd(&counts[ei[e]], 1);  // ei[0..E) = dst row
}

__global__ __launch_bounds__(256) void k_scanA(const int* __restrict__ counts,
                                               int* __restrict__ exOut,
                                               int* __restrict__ blockSum, int n) {
    __shared__ int lds[256];
    int t = threadIdx.x;
    int base = blockIdx.x * 1024 + t * 4;
    int c0 = (base + 0 < n) ? counts[base + 0] : 0;
    int c1 = (base + 1 < n) ? counts[base + 1] : 0;
    int c2 = (base + 2 < n) ? counts[base + 2] : 0;
    int c3 = (base + 3 < n) ? counts[base + 3] : 0;
    int tsum = c0 + c1 + c2 + c3;
    lds[t] = tsum;
    __syncthreads();
    for (int off = 1; off < 256; off <<= 1) {
        int v = (t >= off) ? lds[t - off] : 0;
        __syncthreads();
        lds[t] += v;
        __syncthreads();
    }
    int exBase = lds[t] - tsum;
    if (t == 0) blockSum[blockIdx.x] = lds[255];
    if (base + 0 < n) exOut[base + 0] = exBase;
    if (base + 1 < n) exOut[base + 1] = exBase + c0;
    if (base + 2 < n) exOut[base + 2] = exBase + c0 + c1;
    if (base + 3 < n) exOut[base + 3] = exBase + c0 + c1 + c2;
}

__global__ __launch_bounds__(128) void k_scanB(const int* __restrict__ blockSum,
                                               int* __restrict__ blockOff,
                                               int* __restrict__ offsets, int nb, int n) {
    __shared__ int lds[128];
    int t = threadIdx.x;
    int v = (t < nb) ? blockSum[t] : 0;
    lds[t] = v;
    __syncthreads();
    for (int off = 1; off < 128; off <<= 1) {
        int u = (t >= off) ? lds[t - off] : 0;
        __syncthreads();
        lds[t] += u;
        __syncthreads();
    }
    if (t < nb) blockOff[t] = lds[t] - v;
    if (t == 127) offsets[n] = lds[127];
}

__global__ void k_scanC(const int* __restrict__ exOut, const int* __restrict__ blockOff,
                        int* __restrict__ offsets, int* __restrict__ cursor, int n) {
    int i = blockIdx.x * blockDim.x + threadIdx.x;
    if (i < n) {
        int v = exOut[i] + blockOff[i >> 10];
        offsets[i] = v;
        cursor[i] = v;
    }
}

// XCD-phased scatter: block group (bid & 7) handles dst range
// [p*bucketDiv, (p+1)*bucketDiv). Under round-robin block->XCD dispatch each
// XCD's L2 owns a disjoint 1/8 slice of srcval -> dirty lines accumulate ~8
// entries before writeback instead of 1 (WRITE_SIZE 100MB -> ~15MB).
// Edge data (19 MB) is L3-resident across the 8 sweeps.
__global__ __launch_bounds__(256) void k_scatter(const int* __restrict__ ei,
                                                 const float* __restrict__ vals,
                                                 int* __restrict__ cursor,
                                                 int2* __restrict__ srcval,
                                                 int e_cnt, int bucketDiv,
                                                 int blocksPerPass) {
    int pass = blockIdx.x & 7;
    int bchunk = blockIdx.x >> 3;
    int lo = pass * bucketDiv;
    int stride = blocksPerPass * 256;
    for (int e = bchunk * 256 + threadIdx.x; e < e_cnt; e += stride) {
        int d = ei[e];
        if ((unsigned)(d - lo) < (unsigned)bucketDiv) {
            int s = ei[e_cnt + e];
            float v = vals[e];
            int p = atomicAdd(&cursor[d], 1);
            srcval[p] = make_int2(s, __float_as_int(v));
        }
    }
}

// ---------------------------------------------------------------------------
// Fused SpMM1 + ReLU + GEMM2, one wave per dst row; edge loop unrolled x8.
// ---------------------------------------------------------------------------
__global__ __launch_bounds__(256) void k_spmm1g2(const int* __restrict__ offsets,
                                                 const int2* __restrict__ sv,
                                                 const __half* __restrict__ h1h,
                                                 const float* __restrict__ W2,
                                                 __half* __restrict__ h2h, int n) {
    __shared__ float W2s[D_H * 17];
    __shared__ float rbuf[4][D_H];
    int t = threadIdx.x;
    for (int i = t; i < D_H * D_OUT; i += 256)
        W2s[(i >> 4) * 17 + (i & 15)] = W2[i];

    int lane = t & 63, wid = t >> 6;
    int dst = blockIdx.x * 4 + wid;
    bool valid = dst < n;
    int e0 = 0, e1 = 0;
    if (valid) { e0 = offsets[dst]; e1 = offsets[dst + 1]; }

    float acc = 0.f;
    int e = e0;
    for (; e + 8 <= e1; e += 8) {
        int2 A0 = sv[e + 0], A1 = sv[e + 1], A2 = sv[e + 2], A3 = sv[e + 3];
        int2 A4 = sv[e + 4], A5 = sv[e + 5], A6 = sv[e + 6], A7 = sv[e + 7];
        float g0 = __half2float(h1h[(size_t)A0.x * D_H + lane]);
        float g1 = __half2float(h1h[(size_t)A1.x * D_H + lane]);
        float g2 = __half2float(h1h[(size_t)A2.x * D_H + lane]);
        float g3 = __half2float(h1h[(size_t)A3.x * D_H + lane]);
        float g4 = __half2float(h1h[(size_t)A4.x * D_H + lane]);
        float g5 = __half2float(h1h[(size_t)A5.x * D_H + lane]);
        float g6 = __half2float(h1h[(size_t)A6.x * D_H + lane]);
        float g7 = __half2float(h1h[(size_t)A7.x * D_H + lane]);
        acc = fmaf(__int_as_float(A0.y), g0, acc);
        acc = fmaf(__int_as_float(A1.y), g1, acc);
        acc = fmaf(__int_as_float(A2.y), g2, acc);
        acc = fmaf(__int_as_float(A3.y), g3, acc);
        acc = fmaf(__int_as_float(A4.y), g4, acc);
        acc = fmaf(__int_as_float(A5.y), g5, acc);
        acc = fmaf(__int_as_float(A6.y), g6, acc);
        acc = fmaf(__int_as_float(A7.y), g7, acc);
    }
    for (; e < e1; ++e) {
        int2 A = sv[e];
        acc = fmaf(__int_as_float(A.y), __half2float(h1h[(size_t)A.x * D_H + lane]), acc);
    }
    rbuf[wid][lane] = fmaxf(acc, 0.f);
    __syncthreads();

    int j = lane & 15, g = lane >> 4;
    float s = 0.f;
#pragma unroll
    for (int kk = 0; kk < 16; ++kk)
        s = fmaf(rbuf[wid][g * 16 + kk], W2s[(g * 16 + kk) * 17 + j], s);
    s += __shfl_xor(s, 16);
    s += __shfl_xor(s, 32);
    if (valid && lane < 16) h2h[(size_t)dst * D_OUT + j] = __float2half(s);
}

// ---------------------------------------------------------------------------
// SpMM2 + log_softmax, 16 lanes per dst, edge loop unrolled x4.
// ---------------------------------------------------------------------------
__global__ __launch_bounds__(256) void k_spmm2(const int* __restrict__ offsets,
                                               const int2* __restrict__ sv,
                                               const __half* __restrict__ h2h,
                                               float* __restrict__ out, int n) {
    int t = threadIdx.x;
    int f = t & 15;
    int dst = blockIdx.x * 16 + (t >> 4);
    if (dst >= n) return;
    int e0 = offsets[dst], e1 = offsets[dst + 1];
    float acc = 0.f;
    int e = e0;
    for (; e + 4 <= e1; e += 4) {
        int2 A = sv[e], B = sv[e + 1], C = sv[e + 2], D = sv[e + 3];
        float g0 = __half2float(h2h[(size_t)A.x * D_OUT + f]);
        float g1 = __half2float(h2h[(size_t)B.x * D_OUT + f]);
        float g2 = __half2float(h2h[(size_t)C.x * D_OUT + f]);
        float g3 = __half2float(h2h[(size_t)D.x * D_OUT + f]);
        acc = fmaf(__int_as_float(A.y), g0, acc);
        acc = fmaf(__int_as_float(B.y), g1, acc);
        acc = fmaf(__int_as_float(C.y), g2, acc);
        acc = fmaf(__int_as_float(D.y), g3, acc);
    }
    for (; e < e1; ++e) {
        int2 A = sv[e];
        acc = fmaf(__int_as_float(A.y), __half2float(h2h[(size_t)A.x * D_OUT + f]), acc);
    }
    float m = acc;
#pragma unroll
    for (int d = 1; d < 16; d <<= 1) m = fmaxf(m, __shfl_xor(m, d, 16));
    float ex = expf(acc - m);
    float sum = ex;
#pragma unroll
    for (int d = 1; d < 16; d <<= 1) sum += __shfl_xor(sum, d, 16);
    out[(size_t)dst * D_OUT + f] = acc - m - logf(sum);
}

// ---------------------------------------------------------------------------
extern "C" void kernel_launch(void* const* d_in, const int* in_sizes, int n_in,
                              void* d_out, int out_size, void* d_ws, size_t ws_size,
                              hipStream_t stream) {
    const float* x  = (const float*)d_in[0];
    const float* W1 = (const float*)d_in[1];
    const float* W2 = (const float*)d_in[2];
    const float* ev = (const float*)d_in[3];
    const int*   ei = (const int*)d_in[4];
    float* out = (float*)d_out;

    int n     = in_sizes[0] / D_IN;  // 100000
    int e_cnt = in_sizes[3];         // 1600000

    int2*   srcval = (int2*)d_ws;                       // e_cnt
    __half* h1h    = (__half*)(srcval + e_cnt);         // n*64
    __half* h2h    = h1h + (size_t)n * D_H;             // n*16
    int* counts    = (int*)(h2h + (size_t)n * D_OUT);   // n
    int* exOut     = counts + n;                        // n
    int* blockSum  = exOut + n;                         // <=128
    int* blockOff  = blockSum + 128;                    // <=128
    int* offsets   = blockOff + 128;                    // n+1
    int* cursor    = offsets + n + 1;                   // n

    hipMemsetAsync(counts, 0, (size_t)n * sizeof(int), stream);

    int nb_scan = (n + 1023) / 1024;
    int bucketDiv = (n + 7) / 8;         // dst range per XCD pass
    int blocksPerPass = 256;             // grid = 8*256 = 2048 blocks

    k_gemm1  <<<(n + 63) / 64, 1024, 0, stream>>>(x, W1, h1h, n);
    k_hist   <<<(e_cnt + 255) / 256, 256, 0, stream>>>(ei, counts, e_cnt);
    k_scanA  <<<nb_scan, 256, 0, stream>>>(counts, exOut, blockSum, n);
    k_scanB  <<<1, 128, 0, stream>>>(blockSum, blockOff, offsets, nb_scan, n);
    k_scanC  <<<(n + 255) / 256, 256, 0, stream>>>(exOut, blockOff, offsets, cursor, n);
    k_scatter<<<8 * blocksPerPass, 256, 0, stream>>>(ei, ev, cursor, srcval, e_cnt,
                                                     bucketDiv, blocksPerPass);
    k_spmm1g2<<<(n + 3) / 4, 256, 0, stream>>>(offsets, srcval, h1h, W2, h2h, n);
    k_spmm2  <<<(n + 15) / 16, 256, 0, stream>>>(offsets, srcval, h2h, out, n);
}